// Round 1
// baseline (325.647 us; speedup 1.0000x reference)
//
#include <hip/hip_runtime.h>
#include <stdint.h>

// Problem constants
#define B_  16
#define C_  256
#define H_  64
#define W_  64
#define P_  4096      // H*W
#define E_  8
#define HP_ 66        // padded spatial (64 + 2)

typedef __bf16 bf16x8 __attribute__((ext_vector_type(8)));
typedef float  f32x4  __attribute__((ext_vector_type(4)));

// ---------- helpers ----------
__device__ __forceinline__ unsigned short f2bf(float f) {
    union { float f; unsigned int u; } v; v.f = f;
    unsigned int u = v.u;
    unsigned int r = (u + 0x7fffu + ((u >> 16) & 1u)) >> 16;  // RNE
    return (unsigned short)r;
}

__device__ __forceinline__ void async_load16(const void* g, void* l) {
    __builtin_amdgcn_global_load_lds(
        (const __attribute__((address_space(1))) void*)g,
        (__attribute__((address_space(3))) void*)l, 16, 0, 0);
}

// ---------- k1: xmean[b][c] = mean_hw x[b][c][:][:] ----------
__global__ void k_xmean(const float* __restrict__ x, float* __restrict__ xmean) {
    const int bid = blockIdx.x;             // b*256 + c
    const int tid = threadIdx.x;
    const float* p = x + (size_t)bid * P_;
    float s = 0.f;
#pragma unroll
    for (int k = 0; k < P_ / 256; ++k) s += p[tid + k * 256];
    for (int off = 32; off; off >>= 1) s += __shfl_down(s, off, 64);
    __shared__ float w4[4];
    if ((tid & 63) == 0) w4[tid >> 6] = s;
    __syncthreads();
    if (tid == 0) xmean[bid] = (w4[0] + w4[1] + w4[2] + w4[3]) * (1.0f / P_);
}

// ---------- k2: mix[b][e] = softmax_e(dense(conv_w @ xmean + cb) + db) ----------
__global__ void k_mix(const float* __restrict__ xmean,
                      const float* __restrict__ cw, const float* __restrict__ cb,
                      const float* __restrict__ dw, const float* __restrict__ db,
                      float* __restrict__ mix) {
    const int b = blockIdx.x, tid = threadIdx.x;
    __shared__ float sxm[256];
    __shared__ float spool[256];
    __shared__ float sl[8];
    sxm[tid] = xmean[b * 256 + tid];
    __syncthreads();
    float a = cb[tid];
    for (int c = 0; c < 256; ++c) a += cw[tid * 256 + c] * sxm[c];
    spool[tid] = a;
    __syncthreads();
    if (tid < 8) {
        float l = db[tid];
        for (int d = 0; d < 256; ++d) l += dw[tid * 256 + d] * spool[d];
        sl[tid] = l;
    }
    __syncthreads();
    if (tid < 8) {
        float m = sl[0];
        for (int e = 1; e < 8; ++e) m = fmaxf(m, sl[e]);
        float den = 0.f;
        for (int e = 0; e < 8; ++e) den += __expf(sl[e] - m);
        mix[b * 8 + tid] = __expf(sl[tid] - m) / den;
    }
}

// ---------- k3: Wg[b][o][t][ic] = bf16( sum_e mix[b][e] * KE[e][o][ic][t] ) ----------
// KE flat: ((e*256 + o)*256 + ic)*9 + t   (reshape makes axis1 = OUT channel)
__global__ void k_mixkern(const float* __restrict__ KE, const float* __restrict__ mix,
                          unsigned short* __restrict__ Wg) {
    const int o = blockIdx.x;       // 0..255
    const int ic = threadIdx.x;     // 0..255
    __shared__ float smix[128];
    if (ic < 128) smix[ic] = mix[ic];
    __syncthreads();
    for (int t = 0; t < 9; ++t) {
        float v[8];
#pragma unroll
        for (int e = 0; e < 8; ++e)
            v[e] = KE[((size_t)(e * 256 + o) * 256 + ic) * 9 + t];
#pragma unroll
        for (int b = 0; b < 16; ++b) {
            float acc = 0.f;
#pragma unroll
            for (int e = 0; e < 8; ++e) acc += smix[b * 8 + e] * v[e];
            Wg[((size_t)(b * 256 + o) * 9 + t) * 256 + ic] = f2bf(acc);
        }
    }
}

// ---------- k4: Xp[b][h+1][w+1][c] = bf16(x[b][c][h][w])  (interior) ----------
__global__ void k_xpose(const float* __restrict__ x, unsigned short* __restrict__ Xp) {
    const int bid = blockIdx.x;       // 16 * 64 * 4
    const int b  = bid >> 8;
    const int h  = (bid >> 2) & 63;
    const int cg = bid & 3;
    const int c0 = cg << 6;
    const int tid = threadIdx.x;
    __shared__ float tile[64][65];
    {
        const int ci = tid >> 2, wseg = tid & 3;
        const float* src = x + ((size_t)(b * 256 + c0 + ci) << 12) + (h << 6) + wseg * 16;
#pragma unroll
        for (int i = 0; i < 4; ++i) {
            float4 v = *(const float4*)(src + i * 4);
            tile[ci][wseg * 16 + i * 4 + 0] = v.x;
            tile[ci][wseg * 16 + i * 4 + 1] = v.y;
            tile[ci][wseg * 16 + i * 4 + 2] = v.z;
            tile[ci][wseg * 16 + i * 4 + 3] = v.w;
        }
    }
    __syncthreads();
    {
        const int w = tid >> 2, cs = tid & 3;
        unsigned short ov[16] __attribute__((aligned(16)));
#pragma unroll
        for (int k = 0; k < 16; ++k) ov[k] = f2bf(tile[cs * 16 + k][w]);
        unsigned short* dst = Xp + ((size_t)((b * HP_ + h + 1) * HP_ + (w + 1)) << 8) + c0 + cs * 16;
        ((uint4*)dst)[0] = ((const uint4*)ov)[0];
        ((uint4*)dst)[1] = ((const uint4*)ov)[1];
    }
}

// ---------- k5: zero the pad border of Xp ----------
__global__ void k_border(unsigned short* __restrict__ Xp) {
    const int gid = blockIdx.x * 256 + threadIdx.x;   // 0..133119
    const int pix = gid >> 5;                          // 0..4159 (16*260)
    const int chunk = gid & 31;
    const int b = pix / 260;
    const int j = pix - b * 260;
    int h, w;
    if (j < 66)       { h = 0;  w = j; }
    else if (j < 132) { h = 65; w = j - 66; }
    else { int jj = j - 132; h = 1 + (jj & 63); w = (jj < 64) ? 0 : 65; }
    const uint4 z = {0u, 0u, 0u, 0u};
    *(uint4*)(Xp + ((size_t)((b * HP_ + h) * HP_ + w) << 8) + chunk * 8) = z;
}

// ---------- k6: implicit-im2col bf16 MFMA GEMM ----------
// Per block: sample b, 128 output channels, 128 pixels (2 rows x 64).
// K = 9 taps * 256 ch = 2304, BK = 64. A = Wg[b][o][k], B^T = Xp pixel rows.
__global__ __launch_bounds__(256) void k_gemm(const unsigned short* __restrict__ Wg,
                                              const unsigned short* __restrict__ Xp,
                                              float* __restrict__ out) {
    __shared__ __align__(16) unsigned short lA[128 * 64];
    __shared__ __align__(16) unsigned short lB[128 * 64];
    const int tid = threadIdx.x;
    const int bid = blockIdx.x;
    const int b   = bid >> 6;
    const int rem = bid & 63;
    const int ot  = rem & 1;
    const int rp  = rem >> 1;
    const int o0  = ot << 7;
    const int h0  = rp << 1;

    const int wid  = tid >> 6;
    const int lane = tid & 63;
    const int wm   = wid >> 1;
    const int wn   = wid & 1;
    const int ql   = lane & 15;
    const int quad = lane >> 4;

    const int srow = tid >> 3;    // 0..31
    const int sseg = tid & 7;     // 0..7

    f32x4 acc[4][4];
#pragma unroll
    for (int i = 0; i < 4; ++i)
#pragma unroll
        for (int j = 0; j < 4; ++j) acc[i][j] = (f32x4)0.0f;

    char* lAb = (char*)lA;
    char* lBb = (char*)lB;
    // A element index: ((b*256 + o0 + srow + 32j)*9 + t)*256 + kc*64 + sseg*8
    const size_t abase = (size_t)(b * 256 + o0 + srow) * 9 * 256 + sseg * 8;

    for (int t = 0; t < 9; ++t) {
        const int kh = t / 3;
        const int kw = t - kh * 3;
        for (int kc = 0; kc < 4; ++kc) {
#pragma unroll
            for (int j = 0; j < 4; ++j) {
                const unsigned short* ga = Wg + abase + (size_t)j * 32 * 9 * 256
                                           + (size_t)t * 256 + kc * 64;
                async_load16(ga, lAb + tid * 16 + j * 4096);
            }
#pragma unroll
            for (int j = 0; j < 4; ++j) {
                const int pix = srow + 32 * j;
                const int pr  = pix >> 6;
                const int w   = pix & 63;
                const unsigned short* gb = Xp
                    + ((size_t)((b * HP_ + h0 + pr + kh) * HP_ + (w + kw)) << 8)
                    + kc * 64 + sseg * 8;
                async_load16(gb, lBb + tid * 16 + j * 4096);
            }
            __syncthreads();
#pragma unroll
            for (int kk = 0; kk < 2; ++kk) {
                bf16x8 af[4], bv[4];
#pragma unroll
                for (int mi = 0; mi < 4; ++mi)
                    af[mi] = *(const bf16x8*)(lAb + (((wm * 64 + mi * 16 + ql) * 64) + kk * 32 + quad * 8) * 2);
#pragma unroll
                for (int ni = 0; ni < 4; ++ni)
                    bv[ni] = *(const bf16x8*)(lBb + (((wn * 64 + ni * 16 + ql) * 64) + kk * 32 + quad * 8) * 2);
#pragma unroll
                for (int mi = 0; mi < 4; ++mi)
#pragma unroll
                    for (int ni = 0; ni < 4; ++ni)
                        acc[mi][ni] = __builtin_amdgcn_mfma_f32_16x16x32_bf16(
                            af[mi], bv[ni], acc[mi][ni], 0, 0, 0);
            }
            __syncthreads();
        }
    }

    // Epilogue: C/D layout col=lane&15 (pixel), row=quad*4+reg (o)
    const int h = h0 + wn;
#pragma unroll
    for (int mi = 0; mi < 4; ++mi) {
        const int o = o0 + wm * 64 + mi * 16 + quad * 4;
#pragma unroll
        for (int ni = 0; ni < 4; ++ni) {
            const int w = ni * 16 + ql;
            float* po = out + ((size_t)(b * 256 + o) << 12) + (h << 6) + w;
#pragma unroll
            for (int r = 0; r < 4; ++r) po[(size_t)r << 12] = acc[mi][ni][r];
        }
    }
}

// ---------- launch ----------
extern "C" void kernel_launch(void* const* d_in, const int* in_sizes, int n_in,
                              void* d_out, int out_size, void* d_ws, size_t ws_size,
                              hipStream_t stream) {
    const float* x  = (const float*)d_in[0];
    const float* KE = (const float*)d_in[1];
    const float* cw = (const float*)d_in[2];
    const float* cb = (const float*)d_in[3];
    const float* dw = (const float*)d_in[4];
    const float* db = (const float*)d_in[5];
    float* out = (float*)d_out;

    char* ws = (char*)d_ws;
    float* xmean          = (float*)(ws + 0);            // 16*256*4    = 16 KB
    float* mix            = (float*)(ws + 16384);        // 16*8*4      = 512 B
    unsigned short* Wg    = (unsigned short*)(ws + 32768);          // 16*256*9*256*2 = 18.87 MB
    unsigned short* Xp    = (unsigned short*)(ws + 32768 + 18874368); // 16*66*66*256*2 = 35.68 MB
    // total ws use ~54.6 MB

    k_xmean  <<<dim3(B_ * C_),        dim3(256), 0, stream>>>(x, xmean);
    k_mix    <<<dim3(B_),             dim3(256), 0, stream>>>(xmean, cw, cb, dw, db, mix);
    k_mixkern<<<dim3(C_),             dim3(256), 0, stream>>>(KE, mix, Wg);
    k_xpose  <<<dim3(B_ * H_ * 4),    dim3(256), 0, stream>>>(x, Xp);
    k_border <<<dim3(520),            dim3(256), 0, stream>>>(Xp);
    k_gemm   <<<dim3(B_ * 2 * 32),    dim3(256), 0, stream>>>(Wg, Xp, out);
}

// Round 2
// 264.280 us; speedup vs baseline: 1.2322x; 1.2322x over previous
//
#include <hip/hip_runtime.h>
#include <stdint.h>

// Problem constants
#define B_  16
#define C_  256
#define H_  64
#define W_  64
#define P_  4096      // H*W
#define E_  8
#define HP_ 66        // padded spatial (64 + 2)

typedef __bf16 bf16x8 __attribute__((ext_vector_type(8)));
typedef float  f32x4  __attribute__((ext_vector_type(4)));

// ---------- helpers ----------
__device__ __forceinline__ unsigned short f2bf(float f) {
    union { float f; unsigned int u; } v; v.f = f;
    unsigned int u = v.u;
    unsigned int r = (u + 0x7fffu + ((u >> 16) & 1u)) >> 16;  // RNE
    return (unsigned short)r;
}

__device__ __forceinline__ void async_load16(const void* g, void* l) {
    __builtin_amdgcn_global_load_lds(
        (const __attribute__((address_space(1))) void*)g,
        (__attribute__((address_space(3))) void*)l, 16, 0, 0);
}

// ---------- k_xpose: Xp[b][h+1][w+1][c] = bf16(x[b][c][h][w]) + fused channel-sum ----------
__global__ void k_xpose(const float* __restrict__ x, unsigned short* __restrict__ Xp,
                        float* __restrict__ xsum) {
    const int bid = blockIdx.x;       // 16 * 64 * 4
    const int b  = bid >> 8;
    const int h  = (bid >> 2) & 63;
    const int cg = bid & 3;
    const int c0 = cg << 6;
    const int tid = threadIdx.x;
    __shared__ float tile[64][65];
    {
        const int ci = tid >> 2, wseg = tid & 3;
        const float* src = x + ((size_t)(b * 256 + c0 + ci) << 12) + (h << 6) + wseg * 16;
        float s = 0.f;
#pragma unroll
        for (int i = 0; i < 4; ++i) {
            float4 v = *(const float4*)(src + i * 4);
            tile[ci][wseg * 16 + i * 4 + 0] = v.x;
            tile[ci][wseg * 16 + i * 4 + 1] = v.y;
            tile[ci][wseg * 16 + i * 4 + 2] = v.z;
            tile[ci][wseg * 16 + i * 4 + 3] = v.w;
            s += v.x + v.y + v.z + v.w;
        }
        // reduce the 4 wseg lanes (consecutive) and add to channel sum
        s += __shfl_down(s, 1, 64);
        s += __shfl_down(s, 2, 64);
        if ((tid & 3) == 0) atomicAdd(&xsum[b * 256 + c0 + ci], s);
    }
    __syncthreads();
    {
        const int w = tid >> 2, cs = tid & 3;
        unsigned short ov[16] __attribute__((aligned(16)));
#pragma unroll
        for (int k = 0; k < 16; ++k) ov[k] = f2bf(tile[cs * 16 + k][w]);
        unsigned short* dst = Xp + ((size_t)((b * HP_ + h + 1) * HP_ + (w + 1)) << 8) + c0 + cs * 16;
        ((uint4*)dst)[0] = ((const uint4*)ov)[0];
        ((uint4*)dst)[1] = ((const uint4*)ov)[1];
    }
}

// ---------- k_mix: mix[b][e] = softmax_e(dense(conv_w @ xmean + cb) + db) ----------
__global__ void k_mix(const float* __restrict__ xsum,
                      const float* __restrict__ cw, const float* __restrict__ cb,
                      const float* __restrict__ dw, const float* __restrict__ db,
                      float* __restrict__ mix) {
    const int b = blockIdx.x, tid = threadIdx.x;
    __shared__ float sxm[256];
    __shared__ float spool[256];
    __shared__ float sl[8];
    sxm[tid] = xsum[b * 256 + tid] * (1.0f / P_);
    __syncthreads();
    float a = cb[tid];
    for (int c = 0; c < 256; ++c) a += cw[tid * 256 + c] * sxm[c];
    spool[tid] = a;
    __syncthreads();
    if (tid < 8) {
        float l = db[tid];
        for (int d = 0; d < 256; ++d) l += dw[tid * 256 + d] * spool[d];
        sl[tid] = l;
    }
    __syncthreads();
    if (tid < 8) {
        float m = sl[0];
        for (int e = 1; e < 8; ++e) m = fmaxf(m, sl[e]);
        float den = 0.f;
        for (int e = 0; e < 8; ++e) den += __expf(sl[e] - m);
        mix[b * 8 + tid] = __expf(sl[tid] - m) / den;
    }
}

// ---------- k_mixkern: Wg[b][o][t][ic] = bf16( sum_e mix[b][e] * KE[e][o][ic][t] ) ----------
// Coalesced rewrite: block = (o, ic-half); stage 8 x 1152 contiguous floats in LDS.
__global__ void k_mixkern(const float* __restrict__ KE, const float* __restrict__ mix,
                          unsigned short* __restrict__ Wg) {
    const int o    = blockIdx.x >> 1;
    const int half = blockIdx.x & 1;
    const int ic0  = half << 7;
    const int tid  = threadIdx.x;
    __shared__ float s[8][1152];     // 36.9 KB
    __shared__ float smix[128];
    if (tid < 128) smix[tid] = mix[tid];
#pragma unroll
    for (int e = 0; e < 8; ++e) {
        const float* src = KE + (size_t)(e * 256 + o) * 2304 + ic0 * 9;
#pragma unroll
        for (int k = 0; k < 4; ++k) s[e][k * 256 + tid] = src[k * 256 + tid];
        if (tid < 128) s[e][1024 + tid] = src[1024 + tid];
    }
    __syncthreads();
    const int icl = tid & 127;
    const int b0  = (tid >> 7) << 3;     // 0 or 8
#pragma unroll
    for (int t = 0; t < 9; ++t) {
        float v[8];
#pragma unroll
        for (int e = 0; e < 8; ++e) v[e] = s[e][icl * 9 + t];
#pragma unroll
        for (int bb = 0; bb < 8; ++bb) {
            const int b = b0 + bb;
            float acc = 0.f;
#pragma unroll
            for (int e = 0; e < 8; ++e) acc += smix[b * 8 + e] * v[e];
            Wg[((size_t)(b * 256 + o) * 9 + t) * 256 + ic0 + icl] = f2bf(acc);
        }
    }
}

// ---------- k_border: zero the pad border of Xp ----------
__global__ void k_border(unsigned short* __restrict__ Xp) {
    const int gid = blockIdx.x * 256 + threadIdx.x;   // 0..133119
    const int pix = gid >> 5;                          // 0..4159 (16*260)
    const int chunk = gid & 31;
    const int b = pix / 260;
    const int j = pix - b * 260;
    int h, w;
    if (j < 66)       { h = 0;  w = j; }
    else if (j < 132) { h = 65; w = j - 66; }
    else { int jj = j - 132; h = 1 + (jj & 63); w = (jj < 64) ? 0 : 65; }
    const uint4 z = {0u, 0u, 0u, 0u};
    *(uint4*)(Xp + ((size_t)((b * HP_ + h) * HP_ + w) << 8) + chunk * 8) = z;
}

// ---------- k_gemm: implicit-im2col bf16 MFMA GEMM ----------
// Per block: sample b, 128 output channels, 128 pixels (2 rows x 64).
// K = 9 taps * 256 ch = 2304, BK = 64. A = Wg[b][o][k], B^T = Xp pixel rows.
// XCD-pinned: b is derived from bid&7 so each sample's 64 blocks share one L2.
// LDS chunk-slot XOR swizzle (slot = chunk ^ (row&7)) applied on the *global
// source* side of global_load_lds, so fragment ds_read_b128 is conflict-free.
__global__ __launch_bounds__(256) void k_gemm(const unsigned short* __restrict__ Wg,
                                              const unsigned short* __restrict__ Xp,
                                              float* __restrict__ out) {
    __shared__ __align__(16) unsigned short lA[128 * 64];
    __shared__ __align__(16) unsigned short lB[128 * 64];
    const int tid = threadIdx.x;
    const int bid = blockIdx.x;
    const int xcd = bid & 7;
    const int g   = bid >> 3;
    const int b   = xcd + ((g >> 6) << 3);   // all 64 blocks of sample b on one XCD
    const int rem = g & 63;
    const int ot  = rem & 1;
    const int rp  = rem >> 1;
    const int o0  = ot << 7;
    const int h0  = rp << 1;

    const int wid  = tid >> 6;
    const int lane = tid & 63;
    const int wm   = wid >> 1;
    const int wn   = wid & 1;
    const int ql   = lane & 15;
    const int quad = lane >> 4;
    const int sw   = ql & 7;      // read-side swizzle key (= row&7 of fragment row)

    const int srow = tid >> 3;    // 0..31
    const int sseg = tid & 7;     // 0..7  (LDS slot this thread fills)
    const int csrc = sseg ^ (srow & 7);   // global chunk that belongs in this slot

    f32x4 acc[4][4];
#pragma unroll
    for (int i = 0; i < 4; ++i)
#pragma unroll
        for (int j = 0; j < 4; ++j) acc[i][j] = (f32x4)0.0f;

    char* lAb = (char*)lA;
    char* lBb = (char*)lB;
    // A element index: ((b*256 + o0 + srow + 32j)*9 + t)*256 + kc*64 + csrc*8
    const size_t abase = (size_t)(b * 256 + o0 + srow) * 9 * 256 + csrc * 8;

    for (int t = 0; t < 9; ++t) {
        const int kh = t / 3;
        const int kw = t - kh * 3;
        for (int kc = 0; kc < 4; ++kc) {
#pragma unroll
            for (int j = 0; j < 4; ++j) {
                const unsigned short* ga = Wg + abase + (size_t)j * 32 * 9 * 256
                                           + (size_t)t * 256 + kc * 64;
                async_load16(ga, lAb + tid * 16 + j * 4096);
            }
#pragma unroll
            for (int j = 0; j < 4; ++j) {
                const int pix = srow + 32 * j;
                const int pr  = pix >> 6;
                const int w   = pix & 63;
                const unsigned short* gb = Xp
                    + ((size_t)((b * HP_ + h0 + pr + kh) * HP_ + (w + kw)) << 8)
                    + kc * 64 + csrc * 8;
                async_load16(gb, lBb + tid * 16 + j * 4096);
            }
            __syncthreads();
#pragma unroll
            for (int kk = 0; kk < 2; ++kk) {
                bf16x8 af[4], bv[4];
#pragma unroll
                for (int mi = 0; mi < 4; ++mi)
                    af[mi] = *(const bf16x8*)(lAb + (wm * 64 + mi * 16 + ql) * 128
                                              + ((((kk << 2) | quad) ^ sw) << 4));
#pragma unroll
                for (int ni = 0; ni < 4; ++ni)
                    bv[ni] = *(const bf16x8*)(lBb + (wn * 64 + ni * 16 + ql) * 128
                                              + ((((kk << 2) | quad) ^ sw) << 4));
#pragma unroll
                for (int mi = 0; mi < 4; ++mi)
#pragma unroll
                    for (int ni = 0; ni < 4; ++ni)
                        acc[mi][ni] = __builtin_amdgcn_mfma_f32_16x16x32_bf16(
                            af[mi], bv[ni], acc[mi][ni], 0, 0, 0);
            }
            __syncthreads();
        }
    }

    // Epilogue: C/D layout col=lane&15 (pixel), row=quad*4+reg (o)
    const int h = h0 + wn;
#pragma unroll
    for (int mi = 0; mi < 4; ++mi) {
        const int o = o0 + wm * 64 + mi * 16 + quad * 4;
#pragma unroll
        for (int ni = 0; ni < 4; ++ni) {
            const int w = ni * 16 + ql;
            float* po = out + ((size_t)(b * 256 + o) << 12) + (h << 6) + w;
#pragma unroll
            for (int r = 0; r < 4; ++r) po[(size_t)r << 12] = acc[mi][ni][r];
        }
    }
}

// ---------- launch ----------
extern "C" void kernel_launch(void* const* d_in, const int* in_sizes, int n_in,
                              void* d_out, int out_size, void* d_ws, size_t ws_size,
                              hipStream_t stream) {
    const float* x  = (const float*)d_in[0];
    const float* KE = (const float*)d_in[1];
    const float* cw = (const float*)d_in[2];
    const float* cb = (const float*)d_in[3];
    const float* dw = (const float*)d_in[4];
    const float* db = (const float*)d_in[5];
    float* out = (float*)d_out;

    char* ws = (char*)d_ws;
    float* xsum           = (float*)(ws + 0);            // 16*256*4    = 16 KB
    float* mix            = (float*)(ws + 16384);        // 16*8*4      = 512 B
    unsigned short* Wg    = (unsigned short*)(ws + 32768);            // 18.87 MB
    unsigned short* Xp    = (unsigned short*)(ws + 32768 + 18874368); // 35.68 MB

    hipMemsetAsync(xsum, 0, B_ * C_ * sizeof(float), stream);
    k_xpose  <<<dim3(B_ * H_ * 4),    dim3(256), 0, stream>>>(x, Xp, xsum);
    k_border <<<dim3(520),            dim3(256), 0, stream>>>(Xp);
    k_mix    <<<dim3(B_),             dim3(256), 0, stream>>>(xsum, cw, cb, dw, db, mix);
    k_mixkern<<<dim3(C_ * 2),         dim3(256), 0, stream>>>(KE, mix, Wg);
    k_gemm   <<<dim3(B_ * 2 * 32),    dim3(256), 0, stream>>>(Wg, Xp, out);
}